// Round 1
// baseline (426.509 us; speedup 1.0000x reference)
//
#include <hip/hip_runtime.h>
#include <cstddef>

// Problem constants (fixed by setup_inputs).
#define BB   8
#define NN   65536
#define DD   40
#define KK   2
#define PB   128                  // blocks per batch for streaming kernels
#define TPB  256                  // threads per block
#define PPT  (NN / (PB * TPB))    // points per thread = 2
#define NITER 10                  // iteration input is a fixed python scalar (=10);
                                  // host loop count must be capture-time constant.

// ---------- device helpers ----------

__device__ __forceinline__ void load_point(const float* __restrict__ ptr, float x[DD]) {
    const float4* xp = (const float4*)ptr;   // 40 floats = 10 x float4, 16B-aligned (160B rows)
#pragma unroll
    for (int j = 0; j < DD / 4; ++j) {
        float4 v = xp[j];
        x[4 * j + 0] = v.x; x[4 * j + 1] = v.y;
        x[4 * j + 2] = v.z; x[4 * j + 3] = v.w;
    }
}

__device__ __forceinline__ void dists(const float x[DD], const float* __restrict__ c0,
                                      const float* __restrict__ c1, float& d0, float& d1) {
    float s0 = 0.f, s1 = 0.f;
#pragma unroll
    for (int i = 0; i < DD; ++i) {
        float a = x[i] - c0[i];
        float b = x[i] - c1[i];
        s0 = fmaf(a, a, s0);
        s1 = fmaf(b, b, s1);
    }
    d0 = s0; d1 = s1;
}

// Deterministic block reduction of L per-thread values -> dst[0..L)
template <int L>
__device__ __forceinline__ void block_reduce_write(float* vals, float* __restrict__ dst, int tid) {
#pragma unroll
    for (int i = 0; i < L; ++i) {
#pragma unroll
        for (int off = 32; off > 0; off >>= 1)
            vals[i] += __shfl_down(vals[i], off, 64);
    }
    __shared__ float lds[TPB / 64][L];
    const int wave = tid >> 6, lane = tid & 63;
    if (lane == 0) {
#pragma unroll
        for (int i = 0; i < L; ++i) lds[wave][i] = vals[i];
    }
    __syncthreads();
    if (tid < L) {
        float s = 0.f;
#pragma unroll
        for (int w = 0; w < TPB / 64; ++w) s += lds[w][tid];
        dst[tid] = s;
    }
}

// ---------- kernels ----------

// Gather initial centroids: cent[b][k][d] = data[b, ids[b][k], d]
__global__ void k_init(const float* __restrict__ data, const int* __restrict__ ids,
                       float* __restrict__ cent) {
    const int i = threadIdx.x;
    if (i < BB * KK * DD) {
        const int d = i % DD;
        const int k = (i / DD) % KK;
        const int b = i / (KK * DD);
        const int n = ids[b * KK + k];
        cent[i] = data[((size_t)b * NN + n) * DD + d];
    }
}

// Partial per-block sums of x (iteration-invariant total)
__global__ void k_xsum(const float* __restrict__ data, float* __restrict__ partialS) {
    const int pb = blockIdx.x, b = blockIdx.y, tid = threadIdx.x;
    float vals[DD];
#pragma unroll
    for (int i = 0; i < DD; ++i) vals[i] = 0.f;
    const int base = pb * (TPB * PPT);
#pragma unroll
    for (int p = 0; p < PPT; ++p) {
        const int n = base + p * TPB + tid;
        float x[DD];
        load_point(data + ((size_t)b * NN + n) * DD, x);
#pragma unroll
        for (int i = 0; i < DD; ++i) vals[i] += x[i];
    }
    block_reduce_write<DD>(vals, partialS + (size_t)(b * PB + pb) * DD, tid);
}

__global__ void k_reduceS(const float* __restrict__ partialS, float* __restrict__ S) {
    const int i = blockIdx.x * blockDim.x + threadIdx.x;   // B*D = 320
    if (i < BB * DD) {
        const int b = i / DD, d = i % DD;
        float s = 0.f;
        for (int pb = 0; pb < PB; ++pb) s += partialS[(size_t)(b * PB + pb) * DD + d];
        S[i] = s;
    }
}

// Fused soft-assign + weighted accumulation (cluster 0 only; cluster 1 via sum trick)
__global__ void k_accum(const float* __restrict__ data, const float* __restrict__ cent,
                        float* __restrict__ partialP) {
    const int pb = blockIdx.x, b = blockIdx.y, tid = threadIdx.x;
    __shared__ float c0[DD], c1[DD];
    if (tid < DD)            c0[tid]      = cent[(b * KK + 0) * DD + tid];
    else if (tid < 2 * DD)   c1[tid - DD] = cent[(b * KK + 1) * DD + (tid - DD)];
    __syncthreads();

    float vals[DD + 1];
#pragma unroll
    for (int i = 0; i <= DD; ++i) vals[i] = 0.f;

    const int base = pb * (TPB * PPT);
#pragma unroll
    for (int p = 0; p < PPT; ++p) {
        const int n = base + p * TPB + tid;
        float x[DD];
        load_point(data + ((size_t)b * NN + n) * DD, x);
        float d0, d1;
        dists(x, c0, c1, d0, d1);
        // softmax over K=2 of (-d0,-d1): p0 = 1/(1+exp(d0-d1)); saturates cleanly (exp->inf => p0=0)
        const float p0 = 1.f / (1.f + expf(d0 - d1));
        vals[DD] += p0;
#pragma unroll
        for (int i = 0; i < DD; ++i) vals[i] = fmaf(p0, x[i], vals[i]);
    }
    block_reduce_write<DD + 1>(vals, partialP + (size_t)(b * PB + pb) * (DD + 1), tid);
}

// Finalize centroids: c0 = num0/den0 ; c1 = (S - num0)/(N - den0)
__global__ void k_update(const float* __restrict__ partialP, const float* __restrict__ S,
                         float* __restrict__ cent) {
    __shared__ float den0[BB];
    const int tid = threadIdx.x;
    if (tid < BB) {
        float s = 0.f;
        for (int pb = 0; pb < PB; ++pb)
            s += partialP[(size_t)(tid * PB + pb) * (DD + 1) + DD];
        den0[tid] = s;
    }
    __syncthreads();
    if (tid < BB * DD) {
        const int b = tid / DD, d = tid % DD;
        float num = 0.f;
        for (int pb = 0; pb < PB; ++pb)
            num += partialP[(size_t)(b * PB + pb) * (DD + 1) + d];
        const float Sd = S[b * DD + d];
        const float dn = den0[b];
        cent[(b * KK + 0) * DD + d] = num / dn;
        cent[(b * KK + 1) * DD + d] = (Sd - num) / ((float)NN - dn);
    }
}

// Final soft-assign, write probs (B,N,K) as float2 per point
__global__ void k_final(const float* __restrict__ data, const float* __restrict__ cent,
                        float2* __restrict__ out) {
    const int pb = blockIdx.x, b = blockIdx.y, tid = threadIdx.x;
    __shared__ float c0[DD], c1[DD];
    if (tid < DD)            c0[tid]      = cent[(b * KK + 0) * DD + tid];
    else if (tid < 2 * DD)   c1[tid - DD] = cent[(b * KK + 1) * DD + (tid - DD)];
    __syncthreads();

    const int base = pb * (TPB * PPT);
#pragma unroll
    for (int p = 0; p < PPT; ++p) {
        const int n = base + p * TPB + tid;
        float x[DD];
        load_point(data + ((size_t)b * NN + n) * DD, x);
        float d0, d1;
        dists(x, c0, c1, d0, d1);
        const float p0 = 1.f / (1.f + expf(d0 - d1));
        const float p1 = 1.f / (1.f + expf(d1 - d0));
        out[(size_t)b * NN + n] = make_float2(p0, p1);
    }
}

// ---------- launch ----------

extern "C" void kernel_launch(void* const* d_in, const int* in_sizes, int n_in,
                              void* d_out, int out_size, void* d_ws, size_t ws_size,
                              hipStream_t stream) {
    const float* data = (const float*)d_in[0];
    const int*   ids  = (const int*)d_in[1];
    // d_in[2] = iteration (fixed scalar 10); loop count must be capture-time constant.

    float* ws       = (float*)d_ws;
    float* cent     = ws;                                 // B*K*D  = 640
    float* S        = cent + BB * KK * DD;                // B*D    = 320
    float* partialP = S + BB * DD;                        // B*PB*(D+1)
    float* partialS = partialP + BB * PB * (DD + 1);      // B*PB*D
    float2* out     = (float2*)d_out;

    k_init<<<1, 640, 0, stream>>>(data, ids, cent);
    k_xsum<<<dim3(PB, BB), TPB, 0, stream>>>(data, partialS);
    k_reduceS<<<1, 320, 0, stream>>>(partialS, S);
    for (int t = 0; t < NITER; ++t) {
        k_accum<<<dim3(PB, BB), TPB, 0, stream>>>(data, cent, partialP);
        k_update<<<1, 384, 0, stream>>>(partialP, S, cent);
    }
    k_final<<<dim3(PB, BB), TPB, 0, stream>>>(data, cent, out);
}

// Round 2
// 290.247 us; speedup vs baseline: 1.4695x; 1.4695x over previous
//
#include <hip/hip_runtime.h>
#include <cstddef>

// Problem constants (fixed by setup_inputs).
#define BB   8
#define NN   65536
#define DD   40
#define PB   128                  // blocks per batch
#define TPB  256                  // threads per block
#define PPT  2                    // points per thread (NN / (PB*TPB))
#define NITER 10                  // iteration input is a fixed scalar (=10)

// ---------- device helpers ----------

__device__ __forceinline__ float rfl(float x) {
    return __int_as_float(__builtin_amdgcn_readfirstlane(__float_as_int(x)));
}

__device__ __forceinline__ void load_point(const float* __restrict__ ptr, float x[DD]) {
    const float4* xp = (const float4*)ptr;   // 40 floats = 10 x float4 (160B rows, 16B aligned)
#pragma unroll
    for (int j = 0; j < DD / 4; ++j) {
        float4 v = xp[j];
        x[4 * j + 0] = v.x; x[4 * j + 1] = v.y;
        x[4 * j + 2] = v.z; x[4 * j + 3] = v.w;
    }
}

// diff = h - 2*(x.g); 4-way split dot to break the FMA dependency chain
__device__ __forceinline__ float calc_diff(const float x[DD], const float gs[DD], float hs) {
    float a0 = 0.f, a1 = 0.f, a2 = 0.f, a3 = 0.f;
#pragma unroll
    for (int j = 0; j < DD / 4; ++j) {
        a0 = fmaf(x[4 * j + 0], gs[4 * j + 0], a0);
        a1 = fmaf(x[4 * j + 1], gs[4 * j + 1], a1);
        a2 = fmaf(x[4 * j + 2], gs[4 * j + 2], a2);
        a3 = fmaf(x[4 * j + 3], gs[4 * j + 3], a3);
    }
    return fmaf(-2.f, (a0 + a1) + (a2 + a3), hs);
}

__device__ __forceinline__ float prob0(float diff) {
    // softmax over K=2 of (-d0,-d1): p0 = 1/(1+exp(d0-d1)); exp->inf => rcp(inf)=0, clean
    const float e = __expf(diff);
    return __builtin_amdgcn_rcpf(1.f + e);
}

// Deterministic block reduction of L per-thread values -> dst[0..L)
template <int L>
__device__ __forceinline__ void block_reduce_write(float* vals, float* __restrict__ dst, int tid) {
#pragma unroll
    for (int i = 0; i < L; ++i) {
#pragma unroll
        for (int off = 32; off > 0; off >>= 1)
            vals[i] += __shfl_down(vals[i], off, 64);
    }
    __shared__ float lds[TPB / 64][L];
    __syncthreads();   // protect against back-to-back reuse
    const int wave = tid >> 6, lane = tid & 63;
    if (lane == 0) {
#pragma unroll
        for (int i = 0; i < L; ++i) lds[wave][i] = vals[i];
    }
    __syncthreads();
    if (tid < L) {
        float s = 0.f;
#pragma unroll
        for (int w = 0; w < TPB / 64; ++w) s += lds[w][tid];
        dst[tid] = s;
    }
}

// Compute g[], h from initial centroid ids (round 1)
__device__ __forceinline__ void gh_from_ids(const float* __restrict__ data,
                                            const int* __restrict__ ids, int b,
                                            float gs[DD], float& hs, int tid) {
    __shared__ float gbuf[DD], sqbuf[DD], hbuf;
    const int i0 = ids[b * 2 + 0];
    const int i1 = ids[b * 2 + 1];
    if (tid < DD) {
        const float c0 = data[((size_t)b * NN + i0) * DD + tid];
        const float c1 = data[((size_t)b * NN + i1) * DD + tid];
        gbuf[tid]  = c0 - c1;
        sqbuf[tid] = c0 * c0 - c1 * c1;
    }
    __syncthreads();
    if (tid == 0) {
        float h = 0.f;
        for (int i = 0; i < DD; ++i) h += sqbuf[i];
        hbuf = h;
    }
    __syncthreads();
#pragma unroll
    for (int i = 0; i < DD; ++i) gs[i] = rfl(gbuf[i]);
    hs = rfl(hbuf);
    __syncthreads();
}

// Compute g[], h from previous round's partials (every block, redundantly, deterministic)
__device__ __forceinline__ void gh_from_partials(const float* __restrict__ pp,
                                                 const float* __restrict__ S, int b,
                                                 float gs[DD], float& hs, int tid) {
    __shared__ float red[DD + 1];
    __shared__ float gbuf[DD], sqbuf[DD], hbuf;
    if (tid < DD + 1) {
        float s = 0.f;
        const float* base = pp + (size_t)b * PB * (DD + 1) + tid;
#pragma unroll 8
        for (int j = 0; j < PB; ++j) s += base[(size_t)j * (DD + 1)];
        red[tid] = s;
    }
    __syncthreads();
    if (tid < DD) {
        const float den = red[DD];
        const float num = red[tid];
        const float c0 = num / den;
        const float c1 = (S[b * DD + tid] - num) / ((float)NN - den);
        gbuf[tid]  = c0 - c1;
        sqbuf[tid] = c0 * c0 - c1 * c1;
    }
    __syncthreads();
    if (tid == 0) {
        float h = 0.f;
        for (int i = 0; i < DD; ++i) h += sqbuf[i];
        hbuf = h;
    }
    __syncthreads();
#pragma unroll
    for (int i = 0; i < DD; ++i) gs[i] = rfl(gbuf[i]);
    hs = rfl(hbuf);
    __syncthreads();
}

// ---------- kernels ----------

// Round 1: centroids from ids; accumulate P-partials (41) and S-partials (40)
__global__ void k_first(const float* __restrict__ data, const int* __restrict__ ids,
                        float* __restrict__ ppOut, float* __restrict__ psOut) {
    const int pb = blockIdx.x, b = blockIdx.y, tid = threadIdx.x;
    float gs[DD], hs;
    gh_from_ids(data, ids, b, gs, hs, tid);

    float accP[DD + 1], accS[DD];
#pragma unroll
    for (int i = 0; i <= DD; ++i) accP[i] = 0.f;
#pragma unroll
    for (int i = 0; i < DD; ++i) accS[i] = 0.f;

    const int base = pb * (TPB * PPT);
#pragma unroll
    for (int p = 0; p < PPT; ++p) {
        const int n = base + p * TPB + tid;
        float x[DD];
        load_point(data + ((size_t)b * NN + n) * DD, x);
#pragma unroll
        for (int i = 0; i < DD; ++i) accS[i] += x[i];
        const float p0 = prob0(calc_diff(x, gs, hs));
        accP[DD] += p0;
#pragma unroll
        for (int i = 0; i < DD; ++i) accP[i] = fmaf(p0, x[i], accP[i]);
    }
    block_reduce_write<DD + 1>(accP, ppOut + (size_t)(b * PB + pb) * (DD + 1), tid);
    block_reduce_write<DD>(accS, psOut + (size_t)(b * PB + pb) * DD, tid);
}

// One tiny kernel, once: reduce S-partials -> S (B*D = 320)
__global__ void k_reduceS(const float* __restrict__ psIn, float* __restrict__ S) {
    const int i = threadIdx.x + blockIdx.x * blockDim.x;
    if (i < BB * DD) {
        const int b = i / DD, d = i % DD;
        float s = 0.f;
#pragma unroll 8
        for (int pb = 0; pb < PB; ++pb) s += psIn[(size_t)(b * PB + pb) * DD + d];
        S[i] = s;
    }
}

// Rounds 2..10: centroids from previous partials; accumulate new P-partials
__global__ void k_iter(const float* __restrict__ data, const float* __restrict__ ppIn,
                       const float* __restrict__ S, float* __restrict__ ppOut) {
    const int pb = blockIdx.x, b = blockIdx.y, tid = threadIdx.x;
    float gs[DD], hs;
    gh_from_partials(ppIn, S, b, gs, hs, tid);

    float accP[DD + 1];
#pragma unroll
    for (int i = 0; i <= DD; ++i) accP[i] = 0.f;

    const int base = pb * (TPB * PPT);
#pragma unroll
    for (int p = 0; p < PPT; ++p) {
        const int n = base + p * TPB + tid;
        float x[DD];
        load_point(data + ((size_t)b * NN + n) * DD, x);
        const float p0 = prob0(calc_diff(x, gs, hs));
        accP[DD] += p0;
#pragma unroll
        for (int i = 0; i < DD; ++i) accP[i] = fmaf(p0, x[i], accP[i]);
    }
    block_reduce_write<DD + 1>(accP, ppOut + (size_t)(b * PB + pb) * (DD + 1), tid);
}

// Final: centroids from last partials; write probs (B,N,2) as float2
__global__ void k_post(const float* __restrict__ data, const float* __restrict__ ppIn,
                       const float* __restrict__ S, float2* __restrict__ out) {
    const int pb = blockIdx.x, b = blockIdx.y, tid = threadIdx.x;
    float gs[DD], hs;
    gh_from_partials(ppIn, S, b, gs, hs, tid);

    const int base = pb * (TPB * PPT);
#pragma unroll
    for (int p = 0; p < PPT; ++p) {
        const int n = base + p * TPB + tid;
        float x[DD];
        load_point(data + ((size_t)b * NN + n) * DD, x);
        const float p0 = prob0(calc_diff(x, gs, hs));
        out[(size_t)b * NN + n] = make_float2(p0, 1.f - p0);
    }
}

// ---------- launch ----------

extern "C" void kernel_launch(void* const* d_in, const int* in_sizes, int n_in,
                              void* d_out, int out_size, void* d_ws, size_t ws_size,
                              hipStream_t stream) {
    const float* data = (const float*)d_in[0];
    const int*   ids  = (const int*)d_in[1];
    // d_in[2] = iteration (fixed scalar 10); loop count must be capture-time constant.

    float* ws = (float*)d_ws;
    float* pA = ws;                               // B*PB*41
    float* pB = pA + (size_t)BB * PB * (DD + 1);  // B*PB*41
    float* pS = pB + (size_t)BB * PB * (DD + 1);  // B*PB*40
    float* S  = pS + (size_t)BB * PB * DD;        // B*40
    float2* out = (float2*)d_out;

    const dim3 grid(PB, BB);

    k_first<<<grid, TPB, 0, stream>>>(data, ids, pA, pS);
    k_reduceS<<<1, 320, 0, stream>>>(pS, S);

    const float* cur = pA;
    float* nxt = pB;
    for (int t = 0; t < NITER - 1; ++t) {         // rounds 2..10
        k_iter<<<grid, TPB, 0, stream>>>(data, cur, S, nxt);
        const float* tmp = cur; cur = nxt; nxt = (float*)tmp;
    }
    k_post<<<grid, TPB, 0, stream>>>(data, cur, S, out);
}

// Round 3
// 286.461 us; speedup vs baseline: 1.4889x; 1.0132x over previous
//
#include <hip/hip_runtime.h>
#include <cstddef>

// Problem constants (fixed by setup_inputs).
#define BB    8
#define NN    65536
#define DD    40
#define F4    10                 // float4 per point
#define PADF4 11                 // LDS row stride in float4 (odd -> conflict-free b128)
#define TPB   256
#define TILE  256                // points staged per tile
#define TB    2                  // tiles per block
#define PPB   (TILE * TB)        // 512 points per block
#define PB    (NN / PPB)         // 128 blocks per batch
#define NITER 10                 // iteration input is a fixed scalar (=10)

// ---------- device helpers ----------

__device__ __forceinline__ float rfl(float x) {
    return __int_as_float(__builtin_amdgcn_readfirstlane(__float_as_int(x)));
}

__device__ __forceinline__ float prob0(float diff) {
    // p0 = 1/(1+exp(d0-d1)); exp->inf => rcp(inf)=0, clean saturation
    const float e = __expf(diff);
    return __builtin_amdgcn_rcpf(1.f + e);
}

// Deterministic block reduction of L per-thread values -> dst[0..L)
template <int L>
__device__ __forceinline__ void block_reduce_write(float* vals, float* __restrict__ dst, int tid) {
#pragma unroll
    for (int i = 0; i < L; ++i) {
#pragma unroll
        for (int off = 32; off > 0; off >>= 1)
            vals[i] += __shfl_down(vals[i], off, 64);
    }
    __shared__ float lds[TPB / 64][L];
    __syncthreads();
    const int wave = tid >> 6, lane = tid & 63;
    if (lane == 0) {
#pragma unroll
        for (int i = 0; i < L; ++i) lds[wave][i] = vals[i];
    }
    __syncthreads();
    if (tid < L) {
        float s = 0.f;
#pragma unroll
        for (int w = 0; w < TPB / 64; ++w) s += lds[w][tid];
        dst[tid] = s;
    }
}

// g = c0-c1 (to SGPRs), h = |c0|^2-|c1|^2, from initial centroid ids
__device__ __forceinline__ void gh_from_ids(const float* __restrict__ data,
                                            const int* __restrict__ ids, int b,
                                            float gs[DD], float& hs, int tid) {
    __shared__ float gbuf[DD], sqbuf[DD], hbuf;
    if (tid < DD) {
        const int i0 = ids[b * 2 + 0];
        const int i1 = ids[b * 2 + 1];
        const float c0 = data[((size_t)b * NN + i0) * DD + tid];
        const float c1 = data[((size_t)b * NN + i1) * DD + tid];
        gbuf[tid]  = c0 - c1;
        sqbuf[tid] = c0 * c0 - c1 * c1;
    }
    __syncthreads();
    if (tid == 0) {
        float h = 0.f;
#pragma unroll
        for (int i = 0; i < DD; ++i) h += sqbuf[i];
        hbuf = h;
    }
    __syncthreads();
#pragma unroll
    for (int i = 0; i < DD; ++i) gs[i] = rfl(gbuf[i]);
    hs = rfl(hbuf);
}

// Same, from previous round's partials (every block redundantly, deterministic).
// Parallel reduce: 41 cols x 4 quarters of 32 rows each.
__device__ __forceinline__ void gh_from_partials(const float* __restrict__ pp,
                                                 const float* __restrict__ S, int b,
                                                 float gs[DD], float& hs, int tid) {
    __shared__ float part[DD + 1][4];
    __shared__ float gbuf[DD], sqbuf[DD], hbuf;
    const int col = tid >> 2, q = tid & 3;
    if (col <= DD) {
        const float* base = pp + (size_t)b * PB * (DD + 1)
                               + (size_t)q * (PB / 4) * (DD + 1) + col;
        float s = 0.f;
#pragma unroll 8
        for (int j = 0; j < PB / 4; ++j) s += base[(size_t)j * (DD + 1)];
        part[col][q] = s;
    }
    __syncthreads();
    if (tid < DD) {
        const float num = (part[tid][0] + part[tid][1]) + (part[tid][2] + part[tid][3]);
        const float den = (part[DD][0] + part[DD][1]) + (part[DD][2] + part[DD][3]);
        const float c0 = num / den;
        const float c1 = (S[b * DD + tid] - num) / ((float)NN - den);
        gbuf[tid]  = c0 - c1;
        sqbuf[tid] = c0 * c0 - c1 * c1;
    }
    __syncthreads();
    if (tid == 0) {
        float h = 0.f;
#pragma unroll
        for (int i = 0; i < DD; ++i) h += sqbuf[i];
        hbuf = h;
    }
    __syncthreads();
#pragma unroll
    for (int i = 0; i < DD; ++i) gs[i] = rfl(gbuf[i]);
    hs = rfl(hbuf);
}

// ---------- kernels ----------

// MODE 0: first round (centroids from ids), write P-partials
// MODE 1: iter round (centroids from partials), write P-partials
// MODE 2: final round, write probs
template <int MODE>
__global__ __launch_bounds__(TPB, 3) void k_pass(const float* __restrict__ data,
                                                 const int* __restrict__ ids,
                                                 const float* __restrict__ ppIn,
                                                 const float* __restrict__ S,
                                                 float* __restrict__ ppOut,
                                                 float2* __restrict__ out) {
    const int pb = blockIdx.x, b = blockIdx.y, tid = threadIdx.x;
    __shared__ float4 ldsT[TILE * PADF4];     // 45056 B

    const int pBase = pb * PPB;
    const float4* src = (const float4*)data + ((size_t)b * NN + pBase) * F4;

    // stage tile 0 early (independent of the gh preamble)
#pragma unroll
    for (int j = 0; j < F4; ++j) {
        const unsigned f = tid + j * TPB;     // coalesced: lane-consecutive float4s
        ldsT[f + f / 10u] = src[f];           // padded row p*11 + c
    }

    float gs[DD], hs;
    if (MODE == 0) gh_from_ids(data, ids, b, gs, hs, tid);
    else           gh_from_partials(ppIn, S, b, gs, hs, tid);

    float accP[DD + 1];
    if (MODE != 2) {
#pragma unroll
        for (int i = 0; i <= DD; ++i) accP[i] = 0.f;
    }

#pragma unroll
    for (int t = 0; t < TB; ++t) {
        __syncthreads();                      // staged tile visible
        const float4* row = ldsT + tid * PADF4;
        float4 xv[F4];
#pragma unroll
        for (int c = 0; c < F4; ++c) xv[c] = row[c];

        float a0 = 0.f, a1 = 0.f, a2 = 0.f, a3 = 0.f;
#pragma unroll
        for (int c = 0; c < F4; ++c) {
            a0 = fmaf(xv[c].x, gs[4 * c + 0], a0);
            a1 = fmaf(xv[c].y, gs[4 * c + 1], a1);
            a2 = fmaf(xv[c].z, gs[4 * c + 2], a2);
            a3 = fmaf(xv[c].w, gs[4 * c + 3], a3);
        }
        const float p0 = prob0(fmaf(-2.f, (a0 + a1) + (a2 + a3), hs));

        if (MODE == 2) {
            out[(size_t)b * NN + pBase + t * TILE + tid] = make_float2(p0, 1.f - p0);
        } else {
            accP[DD] += p0;
#pragma unroll
            for (int c = 0; c < F4; ++c) {
                accP[4 * c + 0] = fmaf(p0, xv[c].x, accP[4 * c + 0]);
                accP[4 * c + 1] = fmaf(p0, xv[c].y, accP[4 * c + 1]);
                accP[4 * c + 2] = fmaf(p0, xv[c].z, accP[4 * c + 2]);
                accP[4 * c + 3] = fmaf(p0, xv[c].w, accP[4 * c + 3]);
            }
        }
        if (t + 1 < TB) {
            __syncthreads();                  // all reads done before overwrite
            const float4* src2 = src + (size_t)(t + 1) * TILE * F4;
#pragma unroll
            for (int j = 0; j < F4; ++j) {
                const unsigned f = tid + j * TPB;
                ldsT[f + f / 10u] = src2[f];
            }
        }
    }
    if (MODE != 2)
        block_reduce_write<DD + 1>(accP, ppOut + (size_t)(b * PB + pb) * (DD + 1), tid);
}

// One-shot column sum of data -> S-partials (40 accumulators only, no spill)
__global__ __launch_bounds__(TPB, 3) void k_xsum(const float* __restrict__ data,
                                                 float* __restrict__ psOut) {
    const int pb = blockIdx.x, b = blockIdx.y, tid = threadIdx.x;
    __shared__ float4 ldsT[TILE * PADF4];
    const int pBase = pb * PPB;
    const float4* src = (const float4*)data + ((size_t)b * NN + pBase) * F4;

    float4 acc[F4];
#pragma unroll
    for (int c = 0; c < F4; ++c) acc[c] = make_float4(0.f, 0.f, 0.f, 0.f);

#pragma unroll
    for (int t = 0; t < TB; ++t) {
        if (t) __syncthreads();
#pragma unroll
        for (int j = 0; j < F4; ++j) {
            const unsigned f = tid + j * TPB;
            ldsT[f + f / 10u] = src[(size_t)t * TILE * F4 + f];
        }
        __syncthreads();
        const float4* row = ldsT + tid * PADF4;
#pragma unroll
        for (int c = 0; c < F4; ++c) {
            const float4 v = row[c];
            acc[c].x += v.x; acc[c].y += v.y; acc[c].z += v.z; acc[c].w += v.w;
        }
    }
    block_reduce_write<DD>((float*)acc, psOut + (size_t)(b * PB + pb) * DD, tid);
}

__global__ void k_reduceS(const float* __restrict__ psIn, float* __restrict__ S) {
    const int i = threadIdx.x + blockIdx.x * blockDim.x;
    if (i < BB * DD) {
        const int b = i / DD, d = i % DD;
        float s = 0.f;
#pragma unroll 8
        for (int pb = 0; pb < PB; ++pb) s += psIn[(size_t)(b * PB + pb) * DD + d];
        S[i] = s;
    }
}

// ---------- launch ----------

extern "C" void kernel_launch(void* const* d_in, const int* in_sizes, int n_in,
                              void* d_out, int out_size, void* d_ws, size_t ws_size,
                              hipStream_t stream) {
    const float* data = (const float*)d_in[0];
    const int*   ids  = (const int*)d_in[1];
    // d_in[2] = iteration (fixed scalar 10); loop count must be capture-time constant.

    float* ws = (float*)d_ws;
    float* pA = ws;                               // B*PB*41
    float* pB = pA + (size_t)BB * PB * (DD + 1);  // B*PB*41
    float* pS = pB + (size_t)BB * PB * (DD + 1);  // B*PB*40
    float* S  = pS + (size_t)BB * PB * DD;        // B*40
    float2* out = (float2*)d_out;

    const dim3 grid(PB, BB);

    k_pass<0><<<grid, TPB, 0, stream>>>(data, ids, nullptr, nullptr, pA, nullptr);
    k_xsum<<<grid, TPB, 0, stream>>>(data, pS);
    k_reduceS<<<1, 320, 0, stream>>>(pS, S);

    const float* cur = pA;
    float* nxt = pB;
    for (int t = 0; t < NITER - 1; ++t) {         // rounds 2..10
        k_pass<1><<<grid, TPB, 0, stream>>>(data, nullptr, cur, S, nxt, nullptr);
        const float* tmp = cur; cur = nxt; nxt = (float*)tmp;
    }
    k_pass<2><<<grid, TPB, 0, stream>>>(data, nullptr, cur, S, nullptr, out);
}

// Round 4
// 201.701 us; speedup vs baseline: 2.1146x; 1.4202x over previous
//
#include <hip/hip_runtime.h>
#include <cstddef>

// Problem constants (fixed by setup_inputs).
#define BB    8
#define NN    65536
#define DD    40
#define NITER 10                 // iteration input is a fixed scalar (=10)

#define PBLK  32                 // blocks per batch (both big kernels)
// k_prep
#define PTPB  256
#define PTILES 8                 // 8 tiles x 256 pts = 2048 pts/block
#define PADF4 11                 // staging row stride in float4 (conflict-free b128)
// k_pass
#define TPB   512
#define CHUNKS 2                 // 2 chunks x (512 thr x 2 pts) = 2048 pts/block
#define RSTRIDE 44               // reduce-buffer row stride in dwords (16B-aligned, conflict-free)

// ---------- helpers ----------

__device__ __forceinline__ float rfl(float x) {
    return __int_as_float(__builtin_amdgcn_readfirstlane(__float_as_int(x)));
}
__device__ __forceinline__ float prob0(float diff) {
    // p0 = 1/(1+exp(d0-d1)); exp->inf => rcp(inf)=0, clean saturation
    return __builtin_amdgcn_rcpf(1.f + __expf(diff));
}

// Shuffle block reduction (used once per block in k_prep only)
template <int L>
__device__ __forceinline__ void block_reduce_write(float* vals, float* __restrict__ dst, int tid) {
#pragma unroll
    for (int i = 0; i < L; ++i) {
#pragma unroll
        for (int off = 32; off > 0; off >>= 1)
            vals[i] += __shfl_down(vals[i], off, 64);
    }
    __shared__ float lds[PTPB / 64][L];
    __syncthreads();
    const int wave = tid >> 6, lane = tid & 63;
    if (lane == 0) {
#pragma unroll
        for (int i = 0; i < L; ++i) lds[wave][i] = vals[i];
    }
    __syncthreads();
    if (tid < L) {
        float s = 0.f;
#pragma unroll
        for (int w = 0; w < PTPB / 64; ++w) s += lds[w][tid];
        dst[tid] = s;
    }
}

// g = c0-c1, h = |c0|^2-|c1|^2 from initial centroid ids (k_prep)
__device__ __forceinline__ void gh_from_ids(const float* __restrict__ data,
                                            const int* __restrict__ ids, int b,
                                            float gs[DD], float& hs, int tid) {
    __shared__ float gbuf[DD], sqbuf[DD], hbuf;
    if (tid < DD) {
        const int i0 = ids[b * 2 + 0];
        const int i1 = ids[b * 2 + 1];
        const float c0 = data[((size_t)b * NN + i0) * DD + tid];
        const float c1 = data[((size_t)b * NN + i1) * DD + tid];
        gbuf[tid]  = c0 - c1;
        sqbuf[tid] = c0 * c0 - c1 * c1;
    }
    __syncthreads();
    if (tid == 0) {
        float h = 0.f;
#pragma unroll
        for (int i = 0; i < DD; ++i) h += sqbuf[i];
        hbuf = h;
    }
    __syncthreads();
#pragma unroll
    for (int i = 0; i < DD; ++i) gs[i] = rfl(gbuf[i]);
    hs = rfl(hbuf);
    __syncthreads();
}

// g,h from previous round's partials pp[b][32][41] + S (k_pass, TPB=512)
__device__ __forceinline__ void gh_from_partials(const float* __restrict__ pp,
                                                 const float* __restrict__ S, int b,
                                                 float gs[DD], float& hs, int tid) {
    __shared__ float part[DD + 1][8];
    __shared__ float red[DD + 1], gbuf[DD], sqbuf[DD], hbuf;
    if (tid < 328) {
        const int v = tid % 41, q = tid / 41;
        const float* base = pp + (size_t)b * PBLK * (DD + 1);
        float s = 0.f;
#pragma unroll
        for (int r = 0; r < 4; ++r) s += base[(size_t)(q * 4 + r) * (DD + 1) + v];
        part[v][q] = s;
    }
    __syncthreads();
    if (tid <= DD) {
        float s = 0.f;
#pragma unroll
        for (int q = 0; q < 8; ++q) s += part[tid][q];
        red[tid] = s;
    }
    __syncthreads();
    if (tid < DD) {
        const float num = red[tid], den = red[DD];
        const float c0 = num / den;
        const float c1 = (S[b * DD + tid] - num) / ((float)NN - den);
        gbuf[tid]  = c0 - c1;
        sqbuf[tid] = c0 * c0 - c1 * c1;
    }
    __syncthreads();
    if (tid == 0) {
        float h = 0.f;
#pragma unroll
        for (int i = 0; i < DD; ++i) h += sqbuf[i];
        hbuf = h;
    }
    __syncthreads();
#pragma unroll
    for (int i = 0; i < DD; ++i) gs[i] = rfl(gbuf[i]);
    hs = rfl(hbuf);
    __syncthreads();
}

// ---------- kernels ----------

// One-shot: transpose data -> dataT (B,D,N), column sums partials, round-1 prob partials.
__global__ __launch_bounds__(PTPB, 2) void k_prep(const float* __restrict__ data,
                                                  const int* __restrict__ ids,
                                                  float* __restrict__ dataT,
                                                  float* __restrict__ psOut,
                                                  float* __restrict__ ppOut) {
    const int pb = blockIdx.x, b = blockIdx.y, tid = threadIdx.x;
    __shared__ float4 stg[PTPB * PADF4];              // 45056 B

    float gs[DD], hs;
    gh_from_ids(data, ids, b, gs, hs, tid);

    float accS[DD], accP[DD + 1];
#pragma unroll
    for (int i = 0; i < DD; ++i) accS[i] = 0.f;
#pragma unroll
    for (int i = 0; i <= DD; ++i) accP[i] = 0.f;

    for (int t = 0; t < PTILES; ++t) {
        const int basePt = pb * (PTPB * PTILES) + t * PTPB;
        const float4* src = (const float4*)(data + ((size_t)b * NN + basePt) * DD);
        __syncthreads();
#pragma unroll
        for (int j = 0; j < 10; ++j) {
            const unsigned f = tid + j * PTPB;        // coalesced float4 loads
            stg[(f / 10u) * PADF4 + (f % 10u)] = src[f];
        }
        __syncthreads();
        float4 xv[10];
#pragma unroll
        for (int c = 0; c < 10; ++c) xv[c] = stg[tid * PADF4 + c];

        float a0 = 0.f, a1 = 0.f, a2 = 0.f, a3 = 0.f;
#pragma unroll
        for (int c = 0; c < 10; ++c) {
            accS[4 * c + 0] += xv[c].x; accS[4 * c + 1] += xv[c].y;
            accS[4 * c + 2] += xv[c].z; accS[4 * c + 3] += xv[c].w;
            a0 = fmaf(xv[c].x, gs[4 * c + 0], a0);
            a1 = fmaf(xv[c].y, gs[4 * c + 1], a1);
            a2 = fmaf(xv[c].z, gs[4 * c + 2], a2);
            a3 = fmaf(xv[c].w, gs[4 * c + 3], a3);
        }
        const float p0 = prob0(fmaf(-2.f, (a0 + a1) + (a2 + a3), hs));
        accP[DD] += p0;
#pragma unroll
        for (int c = 0; c < 10; ++c) {
            accP[4 * c + 0] = fmaf(p0, xv[c].x, accP[4 * c + 0]);
            accP[4 * c + 1] = fmaf(p0, xv[c].y, accP[4 * c + 1]);
            accP[4 * c + 2] = fmaf(p0, xv[c].z, accP[4 * c + 2]);
            accP[4 * c + 3] = fmaf(p0, xv[c].w, accP[4 * c + 3]);
        }
        // transpose store: comp c of this thread's point, coalesced across lanes
        float* dst = dataT + (size_t)b * DD * NN + basePt + tid;
#pragma unroll
        for (int c = 0; c < 10; ++c) {
            dst[(size_t)(4 * c + 0) * NN] = xv[c].x;
            dst[(size_t)(4 * c + 1) * NN] = xv[c].y;
            dst[(size_t)(4 * c + 2) * NN] = xv[c].z;
            dst[(size_t)(4 * c + 3) * NN] = xv[c].w;
        }
    }
    block_reduce_write<DD + 1>(accP, ppOut + (size_t)(b * PBLK + pb) * (DD + 1), tid);
    block_reduce_write<DD>(accS, psOut + (size_t)(b * PBLK + pb) * DD, tid);
}

// Reduce S-partials (B x 32 x 40) -> S (B x 40); one block of 640 threads
__global__ void k_reduceS(const float* __restrict__ psIn, float* __restrict__ S) {
    const int tid = threadIdx.x;
    __shared__ float tmp[BB * DD][2];
    const int i = tid >> 1, half = tid & 1;
    if (i < BB * DD) {
        const int b = i / DD, d = i % DD;
        float s = 0.f;
#pragma unroll
        for (int r = 0; r < PBLK / 2; ++r)
            s += psIn[(size_t)(b * PBLK + half * (PBLK / 2) + r) * DD + d];
        tmp[i][half] = s;
    }
    __syncthreads();
    if (i < BB * DD && half == 0) S[i] = tmp[i][0] + tmp[i][1];
}

// MODE 1: iter round -> new P-partials.  MODE 2: final round -> probs.
// Operates on dataT; no LDS in the main loop; x kept in registers (float2 = 2 pts/thread).
template <int MODE>
__global__ __launch_bounds__(TPB, 2) void k_pass(const float* __restrict__ dataT,
                                                 const float* __restrict__ ppIn,
                                                 const float* __restrict__ S,
                                                 float* __restrict__ ppOut,
                                                 float* __restrict__ out) {
    const int pb = blockIdx.x, b = blockIdx.y, tid = threadIdx.x;

    float gs[DD], hs;
    gh_from_partials(ppIn, S, b, gs, hs, tid);

    float acc[DD + 1];
    if constexpr (MODE == 1) {
#pragma unroll
        for (int i = 0; i <= DD; ++i) acc[i] = 0.f;
    }

    const float2* colBase = (const float2*)(dataT + (size_t)b * DD * NN);

#pragma unroll
    for (int ch = 0; ch < CHUNKS; ++ch) {
        const int n0 = pb * (TPB * 2 * CHUNKS) + ch * (TPB * 2) + tid * 2;
        const float2* p = colBase + (n0 >> 1);
        float2 x2[DD];
        float da0 = 0.f, da1 = 0.f, db0 = 0.f, db1 = 0.f;
#pragma unroll
        for (int d = 0; d < DD; d += 2) {
            const float2 v0 = p[(size_t)d * (NN / 2)];
            const float2 v1 = p[(size_t)(d + 1) * (NN / 2)];
            x2[d] = v0; x2[d + 1] = v1;
            da0 = fmaf(v0.x, gs[d], da0);     db0 = fmaf(v0.y, gs[d], db0);
            da1 = fmaf(v1.x, gs[d + 1], da1); db1 = fmaf(v1.y, gs[d + 1], db1);
        }
        const float p0a = prob0(fmaf(-2.f, da0 + da1, hs));
        const float p0b = prob0(fmaf(-2.f, db0 + db1, hs));

        if constexpr (MODE == 2) {
            *(float4*)(out + ((size_t)b * NN + n0) * 2) =
                make_float4(p0a, 1.f - p0a, p0b, 1.f - p0b);
        } else {
            acc[DD] += p0a + p0b;
#pragma unroll
            for (int d = 0; d < DD; ++d)
                acc[d] = fmaf(p0a, x2[d].x, fmaf(p0b, x2[d].y, acc[d]));
        }
    }

    if constexpr (MODE == 1) {
        // LDS-transpose reduction: 512 threads x 41 values -> 41 sums
        __shared__ float rbuf[TPB * RSTRIDE];         // 90112 B
        __shared__ float part2[DD + 1][8];
        const int row = tid * RSTRIDE;
#pragma unroll
        for (int c = 0; c < 10; ++c)
            *(float4*)&rbuf[row + 4 * c] =
                make_float4(acc[4 * c], acc[4 * c + 1], acc[4 * c + 2], acc[4 * c + 3]);
        rbuf[row + DD] = acc[DD];
        __syncthreads();
        if (tid < 328) {
            const int v = tid % 41, q = tid / 41;
            float s = 0.f;
            const int base = q * 64 * RSTRIDE + v;
#pragma unroll 8
            for (int j = 0; j < 64; ++j) s += rbuf[base + j * RSTRIDE];
            part2[v][q] = s;
        }
        __syncthreads();
        if (tid <= DD) {
            float s = 0.f;
#pragma unroll
            for (int q = 0; q < 8; ++q) s += part2[tid][q];
            ppOut[(size_t)(b * PBLK + pb) * (DD + 1) + tid] = s;
        }
    }
}

// ---------- launch ----------

extern "C" void kernel_launch(void* const* d_in, const int* in_sizes, int n_in,
                              void* d_out, int out_size, void* d_ws, size_t ws_size,
                              hipStream_t stream) {
    const float* data = (const float*)d_in[0];
    const int*   ids  = (const int*)d_in[1];
    // d_in[2] = iteration (fixed scalar 10); loop count must be capture-time constant.

    float* ws    = (float*)d_ws;
    float* dataT = ws;                                  // B*D*N = 20,971,520 floats (80 MB)
    float* pA    = dataT + (size_t)BB * DD * NN;        // B*32*41
    float* pB    = pA + (size_t)BB * PBLK * (DD + 1);   // B*32*41
    float* pS    = pB + (size_t)BB * PBLK * (DD + 1);   // B*32*40
    float* S     = pS + (size_t)BB * PBLK * DD;         // B*40
    float* out   = (float*)d_out;

    const dim3 grid(PBLK, BB);

    k_prep<<<grid, PTPB, 0, stream>>>(data, ids, dataT, pS, pA);   // round 1 partials
    k_reduceS<<<1, 640, 0, stream>>>(pS, S);

    const float* cur = pA;
    float* nxt = pB;
    for (int t = 0; t < NITER - 1; ++t) {               // rounds 2..10 partials
        k_pass<1><<<grid, TPB, 0, stream>>>(dataT, cur, S, nxt, nullptr);
        const float* tmp = cur; cur = nxt; nxt = (float*)tmp;
    }
    k_pass<2><<<grid, TPB, 0, stream>>>(dataT, cur, S, nullptr, out);  // update #10 + probs
}